// Round 3
// baseline (216.089 us; speedup 1.0000x reference)
//
#include <hip/hip_runtime.h>

// DynamicRouting (CapsNet) on MI355X — R8: fused single kernel + device-scope
// grid barrier; barrier state zeroed by a tiny INIT KERNEL (no hipMemsetAsync),
// spin guard shortened to fail-fast (~15 ms) instead of risking a timeout.
// B=16, I=32, C=8, J=10, D=16, H=W=6 -> DHW=576. num_routing=3 (fixed).
//
// R7 post-mortem: second container death, no counters. Suspects: (a)
// hipMemsetAsync in kernel_launch (not on G9's whitelist of kernel-launch +
// hipMemcpyAsync; a capture tripwire would abort), (b) ~1 s spin guard: any
// barrier malfunction x ~150 replays = minutes -> harness timeout -> dead
// container. R8 eliminates both: init kernel for bar state; guard = 2^17
// polls (~15 ms) so a broken barrier yields a FAST WRONG ANSWER with
// counters, not a dead container.
//
// Co-residency arithmetic (spin safety): 160 blocks <= 256 CUs; 77.8 KiB
// static LDS < 160 KiB/CU (R5 ran 76 KiB fine); 9 waves <= 32/CU; VGPR ~100
// -> every block resident simultaneously -> barrier terminates.
// Visibility: producers' global writes -> __syncthreads -> t0 __threadfence
// (agent release: L2 writeback) -> relaxed arrive; releaser resets counter
// then release-bumps generation; spinners poll relaxed, then __threadfence
// (agent acquire: invalidates this CU's L1 + XCD L2 -> no stale poison, the
// R4 failure mode) -> __syncthreads hands HB to all 576 threads.
//
// Math is R5-verbatim (179 us, absmax 3.8e-6, tripwire-validated): float4
// channel-reduce into LDS; iter 0 with c=0.1; iters 1,2 rebuild sc/b_ij from
// n1/G partials with identical double chains and float casts; squash
// epilogue identical. U2 (11.8 MB write + 23.6 MB re-read), the s buffer,
// and two inter-kernel drains are eliminated; Uv[32] stays in registers.

#define NB   16
#define NI   32
#define NC   8
#define NJ   10
#define ND   16
#define NHW  36
#define NDHW 576
#define NBJ  (NB * NJ)             // 160
#define NJDHW (NJ * NDHW)          // 5760
#define NTOT  (NB * NJ * NDHW)     // 92160
#define EPSV 1e-7f
#define TPB  576                   // 9 waves; one thread per dhw

static __device__ __forceinline__ double wave_sum(double v) {
    #pragma unroll
    for (int off = 32; off > 0; off >>= 1) v += __shfl_down(v, off);
    return v;
}

// block-reduce |sv| over 576 threads -> slot (thread 0 writes)
static __device__ __forceinline__ void n1_reduce(float sv, double* slot,
                                                 double* nred /*[9]*/) {
    int tid = threadIdx.x;
    double a = wave_sum((double)fabsf(sv));
    if ((tid & 63) == 0) nred[tid >> 6] = a;
    __syncthreads();
    if (tid == 0) {
        double t = nred[0];
        #pragma unroll
        for (int w = 1; w < 9; ++w) t += nred[w];
        *slot = t;
    }
}

// block-reduce Uv[i]*sv over 576 threads for all 32 i -> gslot[i]
static __device__ __forceinline__ void g_reduce(const float* Uv, float sv,
                                                double* gslot,
                                                double (*gred)[32] /*[9][32]*/) {
    int tid = threadIdx.x, w = tid >> 6, lane = tid & 63;
    #pragma unroll
    for (int i = 0; i < NI; ++i) {
        double p = wave_sum((double)Uv[i] * (double)sv);
        if (lane == 0) gred[w][i] = p;
    }
    __syncthreads();
    if (tid < NI) {
        double t = gred[0][tid];
        #pragma unroll
        for (int w2 = 1; w2 < 9; ++w2) t += gred[w2][tid];
        gslot[tid] = t;
    }
}

// Device-scope grid barrier. bar[0]=arrive counter, bar[1]=generation.
// All 160 blocks co-resident (see header); guard makes malfunction fail-fast.
static __device__ __forceinline__ void grid_barrier(unsigned* bar) {
    __syncthreads();                       // block's stores are program-prior
    if (threadIdx.x == 0) {
        __threadfence();                   // agent release: L2 writeback
        unsigned g = __hip_atomic_load(&bar[1], __ATOMIC_RELAXED,
                                       __HIP_MEMORY_SCOPE_AGENT);
        unsigned a = __hip_atomic_fetch_add(&bar[0], 1u, __ATOMIC_RELAXED,
                                            __HIP_MEMORY_SCOPE_AGENT);
        if (a == (unsigned)(NBJ - 1)) {
            // last to arrive: reset counter, then publish new generation.
            // release on the gen bump orders the counter reset before it.
            __hip_atomic_store(&bar[0], 0u, __ATOMIC_RELAXED,
                               __HIP_MEMORY_SCOPE_AGENT);
            __hip_atomic_fetch_add(&bar[1], 1u, __ATOMIC_RELEASE,
                                   __HIP_MEMORY_SCOPE_AGENT);
        } else {
            int guard = 0;
            while (__hip_atomic_load(&bar[1], __ATOMIC_RELAXED,
                                     __HIP_MEMORY_SCOPE_AGENT) == g) {
                __builtin_amdgcn_s_sleep(8);
                if (++guard > (1 << 17)) break;   // ~15 ms: wrong, not hung
            }
        }
        __threadfence();                   // agent acquire: inv L1 + XCD L2
    }
    __syncthreads();
}

// Tiny capture-legal initializer for the barrier state (ws is poisoned
// between runs; a kernel launch is the only op G9 guarantees is safe).
__global__ void init_bar(unsigned* bar) {
    if (threadIdx.x < 2) bar[threadIdx.x] = 0u;
}

// ---------------------------------------------------------------------------
// Fused kernel: one block per (b,j); all 3 routing iterations in one launch.
// ---------------------------------------------------------------------------
__global__ __launch_bounds__(TPB) void fused_kernel(
    const float4* __restrict__ uh4, const float* __restrict__ bias,
    double* __restrict__ n1p, double* __restrict__ Gp,
    unsigned* __restrict__ bar, float* __restrict__ out)
{
    __shared__ float4  Utile4[NI * 144];   // 72 KiB: [i][f4] for this (b,j)
    __shared__ double  nred[9];
    __shared__ double  gred[9][32];
    __shared__ double  sc_sh[2][NB];
    __shared__ float   bij_sh[NI * NJ];
    __shared__ float   c_sh[NI];

    const int blk = blockIdx.x;            // b*NJ + j
    const int b = blk / NJ, j = blk - b * NJ;
    const int tid = threadIdx.x;           // dhw in phase 2

    // ---- phase 1: U[b,:,j,:] = sum_c u_hat, float4 (R5 a1 verbatim,
    //      minus the global U2 store) ----
    // u_hat float4 index: ((b*NI+i)*NC + c)*1440 + j*144 + f4
    #pragma unroll
    for (int g = 0; g < 8; ++g) {
        int lin = g * TPB + tid;           // < 4608 = 32*144
        int i  = lin / 144, f4 = lin - i * 144;
        const float4* p = uh4 + ((size_t)(b * NI + i) * NC) * 1440 + j * 144 + f4;
        float4 acc = make_float4(0.f, 0.f, 0.f, 0.f);
        #pragma unroll
        for (int c = 0; c < NC; ++c) {
            float4 v = p[(size_t)c * 1440];
            acc.x += v.x; acc.y += v.y; acc.z += v.z; acc.w += v.w;
        }
        Utile4[lin] = acc;
    }
    __syncthreads();

    // ---- lift Uv column into registers once; reused by all 3 iterations ----
    const float* Utile = (const float*)Utile4;
    float Uv[NI];
    #pragma unroll
    for (int i = 0; i < NI; ++i) Uv[i] = Utile[i * NDHW + tid];
    const float bv = bias[j * ND + tid / NHW];

    // ---- iteration 0 (c = 0.1 exactly) ----
    const float cw = 1.0f / 10.0f;
    float sv = bv;
    #pragma unroll
    for (int i = 0; i < NI; ++i) sv += cw * Uv[i];

    n1_reduce(sv, &n1p[blk], nred);
    g_reduce(Uv, sv, &Gp[(size_t)blk * NI], gred);
    grid_barrier(bar);

    // ---- iterations 1 and 2: R5 ab_kernel prologue verbatim ----
    for (int R = 1; R <= 2; ++R) {
        if (tid < R * NB) {
            int rr = tid / NB, bb = tid - rr * NB;
            double n1 = 0.0;
            #pragma unroll
            for (int jj = 0; jj < NJ; ++jj) n1 += n1p[rr * NBJ + bb * NJ + jj];
            double nsq = n1 * n1;
            sc_sh[rr][bb] = (nsq / (1.0 + nsq)) / (n1 + (double)EPSV);
        }
        __syncthreads();

        if (tid < NI * NJ) {
            int i = tid / NJ, jj = tid - i * NJ;
            double a = 0.0;
            for (int rr = 0; rr < R; ++rr)
                #pragma unroll
                for (int bb = 0; bb < NB; ++bb)
                    a += sc_sh[rr][bb] *
                         Gp[(size_t)(rr * NB + bb) * (NJ * NI) + (size_t)jj * NI + i];
            bij_sh[tid] = (float)a;
        }
        __syncthreads();

        if (tid < NI) {
            float m = -1e30f;
            #pragma unroll
            for (int jj = 0; jj < NJ; ++jj) m = fmaxf(m, bij_sh[tid * NJ + jj]);
            float sum = 0.f;
            #pragma unroll
            for (int jj = 0; jj < NJ; ++jj) sum += expf(bij_sh[tid * NJ + jj] - m);
            c_sh[tid] = expf(bij_sh[tid * NJ + j] - m) / sum;
        }
        __syncthreads();

        // ---- s pass from registers ----
        sv = bv;
        #pragma unroll
        for (int i = 0; i < NI; ++i) sv += c_sh[i] * Uv[i];

        n1_reduce(sv, &n1p[R * NBJ + blk], nred);
        if (R == 1)
            g_reduce(Uv, sv, &Gp[(size_t)(NBJ + blk) * NI], gred);
        grid_barrier(bar);
    }

    // ---- epilogue: v = (n1^2/(1+n1^2)) * (s/(n1+eps)), R5 float exprs ----
    if (tid == 0) {
        double n1 = 0.0;
        #pragma unroll
        for (int jj = 0; jj < NJ; ++jj) n1 += n1p[2 * NBJ + b * NJ + jj];
        nred[0] = n1;
    }
    __syncthreads();
    float n1f = (float)nred[0];
    float nsq = n1f * n1f;
    out[(size_t)blk * NDHW + tid] = (nsq / (1.f + nsq)) * (sv / (n1f + EPSV));
}

extern "C" void kernel_launch(void* const* d_in, const int* in_sizes, int n_in,
                              void* d_out, int out_size, void* d_ws, size_t ws_size,
                              hipStream_t stream)
{
    const float* u_hat = (const float*)d_in[0];
    const float* bias  = (const float*)d_in[1];
    float* out = (float*)d_out;
    // d_in[2] = num_routing, fixed at 3 by the problem.

    // Workspace layout (all 8B-aligned):
    //   n1p : 3*160 doubles   (3,840 B)
    //   Gp  : 2*5120 doubles  (81,920 B)
    //   bar : 2 unsigned      (8 B)      @ byte offset 85,760
    double*   n1p = (double*)d_ws;
    double*   Gp  = n1p + 3 * NBJ;
    unsigned* bar = (unsigned*)(Gp + 2 * NBJ * NI);

    init_bar<<<1, 64, 0, stream>>>(bar);
    fused_kernel<<<NBJ, TPB, 0, stream>>>(
        (const float4*)u_hat, bias, n1p, Gp, bar, out);
}

// Round 4
// 209.321 us; speedup vs baseline: 1.0323x; 1.0323x over previous
//
#include <hip/hip_runtime.h>

// DynamicRouting (CapsNet) on MI355X — R9: back to the harness-proven
// 4-plain-kernel structure (R5), but with a 3x finer grid to fix the
// parallelism starvation R8's counters exposed.
// B=16, I=32, C=8, J=10, D=16, H=W=6 -> DHW=576. num_routing=3 (fixed).
//
// R8 post-mortem: fused kernel PASSED (absmax 3.8e-6 identical) but ran
// 117 us with hbm=5%, VALUBusy=2%, occupancy=16% -> latency-bound, nothing
// busy. Root cause is geometry, not dispatch count: 160 blocks x 576 thr
// puts work on only 160/256 CUs and each phase is a long serial chain per
// block. Fusion + device-scope barriers added wb/inv fence cost for zero
// overlap gain (total 179 -> 216).
//
// R9: split dhw into CK=3 chunks of 192. Grid = (b,j,ck) = 480 blocks x
// 192 threads (3 waves). Per-block phase-1 read drops 590->197 KB; all 256
// CUs engaged (~2 blocks/CU); reduce trees fold 3 waves not 9. Partials
// gain a ck axis (n1p: 480/iter, Gp: 480x32/iter); prologues fold over
// (j,ck). Only f64 re-association changes (~1e-16 rel) -- the f32 s/softmax
// /squash math is R5-verbatim, so absmax should stay ~3.8e-6.
// No cooperative launch, no memset, no spin barrier -- only mechanisms the
// harness has already accepted. U2 staging kept (re-reading u_hat 3x would
// cost 282 MB vs 94+12+24 MB).

#define NB   16
#define NI   32
#define NC   8
#define NJ   10
#define ND   16
#define NHW  36
#define NDHW 576
#define CK   3                     // dhw chunks
#define CHK  192                   // dhw per chunk (= TPB)
#define NBJ  (NB * NJ)             // 160
#define NBJC (NBJ * CK)            // 480 blocks
#define NJDHW (NJ * NDHW)          // 5760
#define NTOT  (NB * NJ * NDHW)     // 92160
#define EPSV 1e-7f
#define TPB  192                   // 3 waves; one thread per dhw-in-chunk

static __device__ __forceinline__ double wave_sum(double v) {
    #pragma unroll
    for (int off = 32; off > 0; off >>= 1) v += __shfl_down(v, off);
    return v;
}

// block-reduce |sv| over 192 threads -> slot (thread 0 writes)
static __device__ __forceinline__ void n1_reduce(float sv, double* slot,
                                                 double* nred /*[3]*/) {
    int tid = threadIdx.x;
    double a = wave_sum((double)fabsf(sv));
    if ((tid & 63) == 0) nred[tid >> 6] = a;
    __syncthreads();
    if (tid == 0) slot[0] = (nred[0] + nred[1]) + nred[2];
}

// block-reduce Uv[i]*sv over 192 threads for all 32 i -> gslot[i]
static __device__ __forceinline__ void g_reduce(const float* Uv, float sv,
                                                double* gslot,
                                                double (*gred)[32] /*[3][32]*/) {
    int tid = threadIdx.x, w = tid >> 6, lane = tid & 63;
    #pragma unroll
    for (int i = 0; i < NI; ++i) {
        double p = wave_sum((double)Uv[i] * (double)sv);
        if (lane == 0) gred[w][i] = p;
    }
    __syncthreads();
    if (tid < NI)
        gslot[tid] = (gred[0][tid] + gred[1][tid]) + gred[2][tid];
}

// ---------------------------------------------------------------------------
// Kernel A1 = channel-reduce (float4) + routing iteration 0 (c == 0.1).
// One block per (b,j,ck), 192 threads.
// Phase 1: 8 float4/thread cover the 32x48 (i,f4) chunk tile; sum over c;
//          store to LDS tile AND to global U2 (coalesced float4).
// Phase 2: iteration-0 math, Uv[i] from LDS (conflict-free).
// ---------------------------------------------------------------------------
__global__ __launch_bounds__(TPB) void a1_kernel(
    const float4* __restrict__ uh4, const float* __restrict__ bias,
    float4* __restrict__ U2f4, double* __restrict__ n1p, double* __restrict__ Gp)
{
    __shared__ float4  Utile4[NI * 48];    // 24 KiB: [i][f4] for this chunk
    __shared__ double  nred[3];
    __shared__ double  gred[3][32];

    const int blk = blockIdx.x;            // (b*NJ + j)*CK + ck
    const int bj = blk / CK, ck = blk - bj * CK;
    const int b = bj / NJ,  j  = bj - b * NJ;
    const int tid = threadIdx.x;           // dhw-in-chunk in phase 2

    // ---- phase 1: U[b,:,j,chunk] = sum_c u_hat, vectorized ----
    // u_hat float4 index: ((b*NI+i)*NC + c)*1440 + j*144 + ck*48 + f4
    #pragma unroll
    for (int g = 0; g < 8; ++g) {
        int lin = g * TPB + tid;           // < 1536 = 32*48
        int i  = lin / 48, f4 = lin - i * 48;
        const float4* p = uh4 + ((size_t)(b * NI + i) * NC) * 1440
                              + j * 144 + ck * 48 + f4;
        float4 acc = make_float4(0.f, 0.f, 0.f, 0.f);
        #pragma unroll
        for (int c = 0; c < NC; ++c) {
            float4 v = p[(size_t)c * 1440];
            acc.x += v.x; acc.y += v.y; acc.z += v.z; acc.w += v.w;
        }
        Utile4[lin] = acc;
        // U2[b][j][i][dhw] as float4: bj*4608 + i*144 + ck*48 + f4
        U2f4[(size_t)bj * 4608 + i * 144 + ck * 48 + f4] = acc;
    }
    __syncthreads();

    // ---- phase 2: iteration 0 (c = 0.1 exactly) ----
    const float* Utile = (const float*)Utile4;
    const float cw = 1.0f / 10.0f;
    float Uv[NI];
    float sv = bias[j * ND + (ck * CHK + tid) / NHW];
    #pragma unroll
    for (int i = 0; i < NI; ++i) {
        Uv[i] = Utile[i * CHK + tid];
        sv += cw * Uv[i];
    }

    n1_reduce(sv, &n1p[blk], nred);
    g_reduce(Uv, sv, &Gp[(size_t)blk * NI], gred);
}

// ---------------------------------------------------------------------------
// Kernel AB<R> = routing iteration R (R=1,2). Prologue redundantly rebuilds
// b_ij from n1p/Gp of iterations 0..R-1 (folding the ck axis), softmaxes,
// then does the s pass. R=1 emits n1p[1],Gp[1]; R=2 emits n1p[2] and s.
// ---------------------------------------------------------------------------
template <int R>
__global__ __launch_bounds__(TPB) void ab_kernel(
    const float* __restrict__ U2, const float* __restrict__ bias,
    const double* __restrict__ n1p, double* __restrict__ Gp,
    double* __restrict__ n1p_out, double* __restrict__ Gp_out,
    float* __restrict__ s)
{
    __shared__ double sc_sh[2][NB];
    __shared__ float  bij_sh[NI * NJ];     // 320
    __shared__ float  c_sh[NI];
    __shared__ double nred[3];
    __shared__ double gred[3][32];

    const int blk = blockIdx.x;            // (b*NJ + j)*CK + ck
    const int bj = blk / CK, ck = blk - bj * CK;
    const int b = bj / NJ,  j  = bj - b * NJ;
    const int tid = threadIdx.x;

    // ---- prologue: sc for each prior iteration (fold j and ck) ----
    if (tid < R * NB) {
        int rr = tid / NB, bb = tid - rr * NB;
        double n1 = 0.0;
        #pragma unroll
        for (int jj = 0; jj < NJ; ++jj)
            #pragma unroll
            for (int cc = 0; cc < CK; ++cc)
                n1 += n1p[(size_t)rr * NBJC + (bb * NJ + jj) * CK + cc];
        double nsq = n1 * n1;
        sc_sh[rr][bb] = (nsq / (1.0 + nsq)) / (n1 + (double)EPSV);
    }
    __syncthreads();

    // ---- b_ij[i,jj] = sum_rr sum_b sum_ck sc*G (320 entries, 192 thr) ----
    for (int e = tid; e < NI * NJ; e += TPB) {
        int i = e / NJ, jj = e - i * NJ;
        double a = 0.0;
        for (int rr = 0; rr < R; ++rr)
            #pragma unroll
            for (int bb = 0; bb < NB; ++bb)
                #pragma unroll
                for (int cc = 0; cc < CK; ++cc)
                    a += sc_sh[rr][bb] *
                         Gp[(size_t)rr * (NBJC * NI) +
                            (size_t)((bb * NJ + jj) * CK + cc) * NI + i];
        bij_sh[e] = (float)a;
    }
    __syncthreads();

    // ---- softmax rows -> c[:, j] ----
    if (tid < NI) {
        float m = -1e30f;
        #pragma unroll
        for (int jj = 0; jj < NJ; ++jj) m = fmaxf(m, bij_sh[tid * NJ + jj]);
        float sum = 0.f;
        #pragma unroll
        for (int jj = 0; jj < NJ; ++jj) sum += expf(bij_sh[tid * NJ + jj] - m);
        c_sh[tid] = expf(bij_sh[tid * NJ + j] - m) / sum;
    }
    __syncthreads();

    // ---- s pass (chunk of 192 dhw) ----
    const float* u2b = U2 + (size_t)bj * 18432 + ck * CHK + tid;
    float Uv[NI];
    float sv = bias[j * ND + (ck * CHK + tid) / NHW];
    #pragma unroll
    for (int i = 0; i < NI; ++i) {
        Uv[i] = u2b[i * NDHW];
        sv += c_sh[i] * Uv[i];
    }

    if (R == 2) s[(size_t)bj * NDHW + ck * CHK + tid] = sv;

    n1_reduce(sv, &n1p_out[blk], nred);
    if (R == 1)
        g_reduce(Uv, sv, &Gp_out[(size_t)blk * NI], gred);
}

// ---------------------------------------------------------------------------
// Kernel V: v = (n1^2/(1+n1^2)) * (s/(n1+eps)). b is wave-uniform
// (5760 % 64 == 0); folds the (j,ck) partials of iteration 2.
// ---------------------------------------------------------------------------
__global__ __launch_bounds__(256) void v_kernel(
    const float* __restrict__ s, const double* __restrict__ n1p2,
    float* __restrict__ out)
{
    int e = blockIdx.x * 256 + threadIdx.x;    // < NTOT exact
    int b = e / NJDHW;
    double n1 = 0.0;
    #pragma unroll
    for (int jj = 0; jj < NJ; ++jj)
        #pragma unroll
        for (int cc = 0; cc < CK; ++cc)
            n1 += n1p2[(b * NJ + jj) * CK + cc];
    float n1f = (float)n1;
    float nsq = n1f * n1f;
    out[e] = (nsq / (1.f + nsq)) * (s[e] / (n1f + EPSV));
}

extern "C" void kernel_launch(void* const* d_in, const int* in_sizes, int n_in,
                              void* d_out, int out_size, void* d_ws, size_t ws_size,
                              hipStream_t stream)
{
    const float* u_hat = (const float*)d_in[0];
    const float* bias  = (const float*)d_in[1];
    // d_in[2] = num_routing, fixed at 3 by the problem.

    float*  U2  = (float*)d_ws;                          // 2,949,120 f (11.8 MB)
    float*  s   = U2 + (size_t)NB * NJ * NI * NDHW;      //    92,160 f
    double* n1p = (double*)(s + NTOT);                   // 3*480 d (8B aligned)
    double* Gp  = n1p + 3 * NBJC;                        // 2*15360 d
    float*  out = (float*)d_out;

    a1_kernel<<<NBJC, TPB, 0, stream>>>(
        (const float4*)u_hat, bias, (float4*)U2, n1p, Gp);
    ab_kernel<1><<<NBJC, TPB, 0, stream>>>(
        U2, bias, n1p, Gp, n1p + NBJC, Gp + NBJC * NI, s);
    ab_kernel<2><<<NBJC, TPB, 0, stream>>>(
        U2, bias, n1p, Gp, n1p + 2 * NBJC, nullptr, s);
    v_kernel<<<NTOT / 256, 256, 0, stream>>>(s, n1p + 2 * NBJC, out);
}